// Round 3
// baseline (56.174 us; speedup 1.0000x reference)
//
#include <hip/hip_runtime.h>
#include <hip/hip_bf16.h>

#define BS 512
#define MARGIN 0.5f
#define FXSCALE 67108864.0  // 2^26

using short8 = __attribute__((ext_vector_type(8))) short;
using f32x4 = __attribute__((ext_vector_type(4))) float;

__device__ inline float waveReduceSum(float v) {
#pragma unroll
    for (int o = 32; o > 0; o >>= 1) v += __shfl_down(v, o, 64);
    return v;
}

// Kernel A: row L2-normalize; write p_bf16 and sq = sum(p*p) (fp32) per row.
// Block 0 thread 0 also zeroes the global accumulators for kernel C.
__global__ __launch_bounds__(256) void knorm(const float* __restrict__ pred,
                                             unsigned short* __restrict__ pb,
                                             float* __restrict__ sq,
                                             unsigned long long* __restrict__ sum_fp,
                                             unsigned int* __restrict__ cnt_g,
                                             unsigned int* __restrict__ done_g) {
    const int i = blockIdx.x;
    const int tid = threadIdx.x;
    if (i == 0 && tid == 0) { *sum_fp = 0ULL; *cnt_g = 0u; *done_g = 0u; }
    __shared__ float sbuf[4];
    const float a0 = pred[i * BS + tid];
    const float a1 = pred[i * BS + tid + 256];
    float ss = a0 * a0 + a1 * a1;
    float w = waveReduceSum(ss);
    const int lane = tid & 63, wid = tid >> 6;
    if (lane == 0) sbuf[wid] = w;
    __syncthreads();
    const float tot = sbuf[0] + sbuf[1] + sbuf[2] + sbuf[3];
    const float m = fmaxf(sqrtf(tot), 1e-10f);
    const float p0 = a0 / m, p1 = a1 / m;
    __hip_bfloat16 h0 = __float2bfloat16(p0);
    __hip_bfloat16 h1 = __float2bfloat16(p1);
    pb[i * BS + tid] = *(unsigned short*)&h0;
    pb[i * BS + tid + 256] = *(unsigned short*)&h1;
    float ss2 = p0 * p0 + p1 * p1;
    __syncthreads();  // protect sbuf reuse
    float w2 = waveReduceSum(ss2);
    if (lane == 0) sbuf[wid] = w2;
    __syncthreads();
    if (tid == 0) sq[i] = sbuf[0] + sbuf[1] + sbuf[2] + sbuf[3];
}

// Kernel B: dist[i][j] = sqrt(max(sq_i + sq_j - 2*dot(p_i,p_j), 0)) via bf16 MFMA.
// One wave per 32x32 output tile; fragment-shaped global loads (L2-resident), no LDS.
__global__ __launch_bounds__(64) void kdist(const unsigned short* __restrict__ pb,
                                            const float* __restrict__ sq,
                                            float* __restrict__ dist) {
    const int lane = threadIdx.x;
    const int r0 = blockIdx.y * 32;
    const int c0 = blockIdx.x * 32;
    const int rl = lane & 15;        // row/col within frag
    const int koff = (lane >> 4) * 8;  // k-chunk per lane group

    f32x4 acc00 = {0.f, 0.f, 0.f, 0.f};
    f32x4 acc01 = {0.f, 0.f, 0.f, 0.f};
    f32x4 acc10 = {0.f, 0.f, 0.f, 0.f};
    f32x4 acc11 = {0.f, 0.f, 0.f, 0.f};

    const unsigned short* pa0 = pb + (r0 + rl) * BS;
    const unsigned short* pa1 = pb + (r0 + rl + 16) * BS;
    const unsigned short* pb0 = pb + (c0 + rl) * BS;
    const unsigned short* pb1 = pb + (c0 + rl + 16) * BS;

#pragma unroll 4
    for (int ks = 0; ks < 16; ++ks) {
        const int k = ks * 32 + koff;
        short8 a0 = *(const short8*)(pa0 + k);
        short8 a1 = *(const short8*)(pa1 + k);
        short8 b0 = *(const short8*)(pb0 + k);
        short8 b1 = *(const short8*)(pb1 + k);
        acc00 = __builtin_amdgcn_mfma_f32_16x16x32_bf16(a0, b0, acc00, 0, 0, 0);
        acc01 = __builtin_amdgcn_mfma_f32_16x16x32_bf16(a0, b1, acc01, 0, 0, 0);
        acc10 = __builtin_amdgcn_mfma_f32_16x16x32_bf16(a1, b0, acc10, 0, 0, 0);
        acc11 = __builtin_amdgcn_mfma_f32_16x16x32_bf16(a1, b1, acc11, 0, 0, 0);
    }

    // C/D layout: col = lane&15, row = (lane>>4)*4 + reg  [m89]
    const int rbase = (lane >> 4) * 4;
#pragma unroll
    for (int fr = 0; fr < 2; ++fr) {
#pragma unroll
        for (int fc = 0; fc < 2; ++fc) {
            f32x4 v = (fr == 0) ? (fc == 0 ? acc00 : acc01) : (fc == 0 ? acc10 : acc11);
            const int col = c0 + fc * 16 + rl;
            const float sqc = sq[col];
#pragma unroll
            for (int r = 0; r < 4; ++r) {
                const int row = r0 + fr * 16 + rbase + r;
                float d2 = sq[row] + sqc - 2.0f * v[r];
                d2 = fmaxf(d2, 0.f);
                dist[row * BS + col] = sqrtf(d2);
            }
        }
    }
}

// Kernel C: per-anchor i (target==1), j-half per blockIdx.y; branchless hinge
// accumulation; deterministic fixed-point global atomics; last block finalizes.
__global__ __launch_bounds__(256) void ktriplet(const float* __restrict__ dist,
                                                const int* __restrict__ target,
                                                unsigned long long* __restrict__ sum_fp,
                                                unsigned int* __restrict__ cnt_g,
                                                unsigned int* __restrict__ done_g,
                                                float* __restrict__ out) {
    const int i = blockIdx.x;
    const int half = blockIdx.y;
    const int tid = threadIdx.x;
    __shared__ float drow[BS];
    __shared__ float maskP[BS];
    __shared__ float sbuf[4];
    __shared__ float cbuf[4];

    for (int t = tid; t < BS; t += 256) {
        drow[t] = dist[i * BS + t];
        maskP[t] = (target[t] == 1 && t != i) ? 1.0f : 0.0f;
    }
    __syncthreads();

    float sum0 = 0.f, sum1 = 0.f, cnt0 = 0.f, cnt1 = 0.f;
    const float dk0 = drow[tid];
    const float dk1 = drow[tid + 256];
    const float nk0 = (target[tid] == 0) ? 1.0f : 0.0f;
    const float nk1 = (target[tid + 256] == 0) ? 1.0f : 0.0f;

    if (target[i] == 1) {
        const int j0 = half * 256;
#pragma unroll 8
        for (int j = j0; j < j0 + 256; ++j) {
            const float pm = maskP[j];
            const float am = drow[j] + MARGIN;
            const float v0 = am - dk0;
            const float v1 = am - dk1;
            sum0 += fmaxf(v0, 0.f) * pm;
            sum1 += fmaxf(v1, 0.f) * pm;
            cnt0 += (v0 > 0.f) ? pm : 0.f;
            cnt1 += (v1 > 0.f) ? pm : 0.f;
        }
    }
    float sum = sum0 * nk0 + sum1 * nk1;
    float cnt = cnt0 * nk0 + cnt1 * nk1;

    float wsm = waveReduceSum(sum);
    float wc = waveReduceSum(cnt);
    const int lane = tid & 63, wid = tid >> 6;
    if (lane == 0) { sbuf[wid] = wsm; cbuf[wid] = wc; }
    __syncthreads();
    if (tid == 0) {
        const float bsum = sbuf[0] + sbuf[1] + sbuf[2] + sbuf[3];
        const float bcnt = cbuf[0] + cbuf[1] + cbuf[2] + cbuf[3];
        // deterministic: integer atomics, order-independent
        unsigned long long fx = (unsigned long long)((double)bsum * FXSCALE + 0.5);
        atomicAdd(sum_fp, fx);
        atomicAdd(cnt_g, (unsigned int)(bcnt + 0.5f));
        __threadfence();
        unsigned int old = atomicAdd(done_g, 1u);
        if (old == 2 * BS - 1) {
            __threadfence();
            unsigned long long s = atomicAdd(sum_fp, 0ULL);
            unsigned int c = atomicAdd(cnt_g, 0u);
            double total = (double)s / FXSCALE;
            out[0] = (float)(total / ((double)c + 1e-7));
        }
    }
}

extern "C" void kernel_launch(void* const* d_in, const int* in_sizes, int n_in,
                              void* d_out, int out_size, void* d_ws, size_t ws_size,
                              hipStream_t stream) {
    const float* pred = (const float*)d_in[0];
    const int* target = (const int*)d_in[1];
    float* out = (float*)d_out;
    char* base = (char*)d_ws;

    unsigned short* pbuf = (unsigned short*)base;                   // 512*512*2B
    float* dist = (float*)(base + 524288);                          // 1 MB
    float* sq = (float*)(base + 1572864);                           // 2 KB
    unsigned long long* sum_fp = (unsigned long long*)(base + 1574912);
    unsigned int* cnt_g = (unsigned int*)(base + 1574920);
    unsigned int* done_g = (unsigned int*)(base + 1574924);

    knorm<<<512, 256, 0, stream>>>(pred, pbuf, sq, sum_fp, cnt_g, done_g);
    dim3 gb(16, 16);
    kdist<<<gb, 64, 0, stream>>>(pbuf, sq, dist);
    dim3 gt(512, 2);
    ktriplet<<<gt, 256, 0, stream>>>(dist, target, sum_fp, cnt_g, done_g, out);
}

// Round 5
// 56.024 us; speedup vs baseline: 1.0027x; 1.0027x over previous
//
#include <hip/hip_runtime.h>
#include <hip/hip_bf16.h>

#define BS 512
#define MARGIN 0.5f
#define FXSCALE 67108864.0  // 2^26

using short8 = __attribute__((ext_vector_type(8))) short;
using f32x4 = __attribute__((ext_vector_type(4))) float;

__device__ inline float waveReduceSum(float v) {
#pragma unroll
    for (int o = 32; o > 0; o >>= 1) v += __shfl_down(v, o, 64);
    return v;
}
__device__ inline unsigned int waveReduceSumU(unsigned int v) {
#pragma unroll
    for (int o = 32; o > 0; o >>= 1) v += __shfl_down(v, o, 64);
    return v;
}

// Kernel A: row L2-normalize; write p_bf16 and sq = sum(p*p) (fp32) per row.
// Block 0 thread 0 also zeroes the global accumulators for kernel C.
__global__ __launch_bounds__(256) void knorm(const float* __restrict__ pred,
                                             unsigned short* __restrict__ pb,
                                             float* __restrict__ sq,
                                             unsigned long long* __restrict__ sum_fp,
                                             unsigned int* __restrict__ cnt_g,
                                             unsigned int* __restrict__ done_g) {
    const int i = blockIdx.x;
    const int tid = threadIdx.x;
    if (i == 0 && tid == 0) { *sum_fp = 0ULL; *cnt_g = 0u; *done_g = 0u; }
    __shared__ float sbuf[4];
    const float a0 = pred[i * BS + tid];
    const float a1 = pred[i * BS + tid + 256];
    float ss = a0 * a0 + a1 * a1;
    float w = waveReduceSum(ss);
    const int lane = tid & 63, wid = tid >> 6;
    if (lane == 0) sbuf[wid] = w;
    __syncthreads();
    const float tot = sbuf[0] + sbuf[1] + sbuf[2] + sbuf[3];
    const float m = fmaxf(sqrtf(tot), 1e-10f);
    const float p0 = a0 / m, p1 = a1 / m;
    __hip_bfloat16 h0 = __float2bfloat16(p0);
    __hip_bfloat16 h1 = __float2bfloat16(p1);
    pb[i * BS + tid] = *(unsigned short*)&h0;
    pb[i * BS + tid + 256] = *(unsigned short*)&h1;
    float ss2 = p0 * p0 + p1 * p1;
    __syncthreads();  // protect sbuf reuse
    float w2 = waveReduceSum(ss2);
    if (lane == 0) sbuf[wid] = w2;
    __syncthreads();
    if (tid == 0) sq[i] = sbuf[0] + sbuf[1] + sbuf[2] + sbuf[3];
}

// Kernel B: dist[i][j] = sqrt(max(sq_i + sq_j - 2*dot(p_i,p_j), 0)) via bf16 MFMA.
// One wave per 32x32 output tile; fragment-shaped global loads (L2-resident), no LDS.
__global__ __launch_bounds__(64) void kdist(const unsigned short* __restrict__ pb,
                                            const float* __restrict__ sq,
                                            float* __restrict__ dist) {
    const int lane = threadIdx.x;
    const int r0 = blockIdx.y * 32;
    const int c0 = blockIdx.x * 32;
    const int rl = lane & 15;
    const int koff = (lane >> 4) * 8;

    f32x4 acc00 = {0.f, 0.f, 0.f, 0.f};
    f32x4 acc01 = {0.f, 0.f, 0.f, 0.f};
    f32x4 acc10 = {0.f, 0.f, 0.f, 0.f};
    f32x4 acc11 = {0.f, 0.f, 0.f, 0.f};

    const unsigned short* pa0 = pb + (r0 + rl) * BS;
    const unsigned short* pa1 = pb + (r0 + rl + 16) * BS;
    const unsigned short* pb0 = pb + (c0 + rl) * BS;
    const unsigned short* pb1 = pb + (c0 + rl + 16) * BS;

#pragma unroll 4
    for (int ks = 0; ks < 16; ++ks) {
        const int k = ks * 32 + koff;
        short8 a0 = *(const short8*)(pa0 + k);
        short8 a1 = *(const short8*)(pa1 + k);
        short8 b0 = *(const short8*)(pb0 + k);
        short8 b1 = *(const short8*)(pb1 + k);
        acc00 = __builtin_amdgcn_mfma_f32_16x16x32_bf16(a0, b0, acc00, 0, 0, 0);
        acc01 = __builtin_amdgcn_mfma_f32_16x16x32_bf16(a0, b1, acc01, 0, 0, 0);
        acc10 = __builtin_amdgcn_mfma_f32_16x16x32_bf16(a1, b0, acc10, 0, 0, 0);
        acc11 = __builtin_amdgcn_mfma_f32_16x16x32_bf16(a1, b1, acc11, 0, 0, 0);
    }

    // C/D layout: col = lane&15, row = (lane>>4)*4 + reg  [m89]
    const int rbase = (lane >> 4) * 4;
#pragma unroll
    for (int fr = 0; fr < 2; ++fr) {
#pragma unroll
        for (int fc = 0; fc < 2; ++fc) {
            f32x4 v = (fr == 0) ? (fc == 0 ? acc00 : acc01) : (fc == 0 ? acc10 : acc11);
            const int col = c0 + fc * 16 + rl;
            const float sqc = sq[col];
#pragma unroll
            for (int r = 0; r < 4; ++r) {
                const int row = r0 + fr * 16 + rbase + r;
                float d2 = sq[row] + sqc - 2.0f * v[r];
                d2 = fmaxf(d2, 0.f);
                dist[row * BS + col] = sqrtf(d2);
            }
        }
    }
}

// Kernel C: per-anchor i (target==1), j-half per blockIdx.y. All distances live
// in registers; mask via +/-inf sentinels; j broadcast via readlane (no LDS in
// the hot loop). Deterministic fixed-point global atomics; last block finalizes.
__global__ __launch_bounds__(256) void ktriplet(const float* __restrict__ dist,
                                                const int* __restrict__ target,
                                                unsigned long long* __restrict__ sum_fp,
                                                unsigned int* __restrict__ cnt_g,
                                                unsigned int* __restrict__ done_g,
                                                float* __restrict__ out) {
    const int i = blockIdx.x;
    const int half = blockIdx.y;
    const int tid = threadIdx.x;
    const int lane = tid & 63;
    const int w = tid >> 6;
    __shared__ float sbuf[4];
    __shared__ unsigned int cbuf[4];

    float sum = 0.f;
    unsigned int cnt = 0;

    if (target[i] == 1) {
        // per-thread registers: slot r covers index idx = r*64 + lane
        float dkn[8];      // negative-masked (k-role):  d or +1e30
        float dkm_all[8];  // positive-masked (j-role):  d or -1e9
#pragma unroll
        for (int r = 0; r < 8; ++r) {
            const int idx = r * 64 + lane;
            const float d = dist[i * BS + idx];   // coalesced, L2-hot
            const int t = target[idx];
            dkn[r] = (t == 0) ? d : 1e30f;
            dkm_all[r] = (t == 1 && idx != i) ? d : -1e9f;
        }
        // this wave's j-chunk: j = (half*4 + w)*64 + jj
        const int rj = half * 4 + w;
        float dkm_j = dkm_all[0];
        dkm_j = (rj == 1) ? dkm_all[1] : dkm_j;
        dkm_j = (rj == 2) ? dkm_all[2] : dkm_j;
        dkm_j = (rj == 3) ? dkm_all[3] : dkm_j;
        dkm_j = (rj == 4) ? dkm_all[4] : dkm_j;
        dkm_j = (rj == 5) ? dkm_all[5] : dkm_j;
        dkm_j = (rj == 6) ? dkm_all[6] : dkm_j;
        dkm_j = (rj == 7) ? dkm_all[7] : dkm_j;

        float s0 = 0.f, s1 = 0.f;
        unsigned int c0 = 0, c1 = 0;
#pragma unroll
        for (int jj = 0; jj < 64; ++jj) {
            const float bc = __int_as_float(
                __builtin_amdgcn_readlane(__float_as_int(dkm_j), jj));
            const float tj = bc + MARGIN;
#pragma unroll
            for (int r = 0; r < 4; ++r) {
                const float v = tj - dkn[r];
                s0 += fmaxf(v, 0.f);
                c0 += (v > 0.f) ? 1u : 0u;
            }
#pragma unroll
            for (int r = 4; r < 8; ++r) {
                const float v = tj - dkn[r];
                s1 += fmaxf(v, 0.f);
                c1 += (v > 0.f) ? 1u : 0u;
            }
        }
        sum = s0 + s1;
        cnt = c0 + c1;
    }

    float wsm = waveReduceSum(sum);
    unsigned int wc = waveReduceSumU(cnt);
    if (lane == 0) { sbuf[w] = wsm; cbuf[w] = wc; }
    __syncthreads();
    if (tid == 0) {
        const float bsum = sbuf[0] + sbuf[1] + sbuf[2] + sbuf[3];
        const unsigned int bcnt = cbuf[0] + cbuf[1] + cbuf[2] + cbuf[3];
        unsigned long long fx = (unsigned long long)((double)bsum * FXSCALE + 0.5);
        atomicAdd(sum_fp, fx);
        atomicAdd(cnt_g, bcnt);
        __threadfence();
        unsigned int old = atomicAdd(done_g, 1u);
        if (old == 2 * BS - 1) {
            __threadfence();
            unsigned long long s = atomicAdd(sum_fp, 0ULL);
            unsigned int c = atomicAdd(cnt_g, 0u);
            double total = (double)s / FXSCALE;
            out[0] = (float)(total / ((double)c + 1e-7));
        }
    }
}

extern "C" void kernel_launch(void* const* d_in, const int* in_sizes, int n_in,
                              void* d_out, int out_size, void* d_ws, size_t ws_size,
                              hipStream_t stream) {
    const float* pred = (const float*)d_in[0];
    const int* target = (const int*)d_in[1];
    float* out = (float*)d_out;
    char* base = (char*)d_ws;

    unsigned short* pbuf = (unsigned short*)base;                   // 512*512*2B
    float* dist = (float*)(base + 524288);                          // 1 MB
    float* sq = (float*)(base + 1572864);                           // 2 KB
    unsigned long long* sum_fp = (unsigned long long*)(base + 1574912);
    unsigned int* cnt_g = (unsigned int*)(base + 1574920);
    unsigned int* done_g = (unsigned int*)(base + 1574924);

    knorm<<<512, 256, 0, stream>>>(pred, pbuf, sq, sum_fp, cnt_g, done_g);
    dim3 gb(16, 16);
    kdist<<<gb, 64, 0, stream>>>(pbuf, sq, dist);
    dim3 gt(512, 2);
    ktriplet<<<gt, 256, 0, stream>>>(dist, target, sum_fp, cnt_g, done_g, out);
}

// Round 6
// 38.589 us; speedup vs baseline: 1.4557x; 1.4518x over previous
//
#include <hip/hip_runtime.h>
#include <hip/hip_bf16.h>

#define BS 512
#define MARGIN 0.5f

using short8 = __attribute__((ext_vector_type(8))) short;
using f32x4 = __attribute__((ext_vector_type(4))) float;

__device__ inline float waveReduceSum(float v) {
#pragma unroll
    for (int o = 32; o > 0; o >>= 1) v += __shfl_down(v, o, 64);
    return v;
}

// Kernel A: row L2-normalize; write p_bf16 and sq = sum(p*p) (fp32) per row.
__global__ __launch_bounds__(256) void knorm(const float* __restrict__ pred,
                                             unsigned short* __restrict__ pb,
                                             float* __restrict__ sq) {
    const int i = blockIdx.x;
    const int tid = threadIdx.x;
    __shared__ float sbuf[4];
    const float a0 = pred[i * BS + tid];
    const float a1 = pred[i * BS + tid + 256];
    float ss = a0 * a0 + a1 * a1;
    float w = waveReduceSum(ss);
    const int lane = tid & 63, wid = tid >> 6;
    if (lane == 0) sbuf[wid] = w;
    __syncthreads();
    const float tot = sbuf[0] + sbuf[1] + sbuf[2] + sbuf[3];
    const float m = fmaxf(sqrtf(tot), 1e-10f);
    const float p0 = a0 / m, p1 = a1 / m;
    __hip_bfloat16 h0 = __float2bfloat16(p0);
    __hip_bfloat16 h1 = __float2bfloat16(p1);
    pb[i * BS + tid] = *(unsigned short*)&h0;
    pb[i * BS + tid + 256] = *(unsigned short*)&h1;
    float ss2 = p0 * p0 + p1 * p1;
    __syncthreads();  // protect sbuf reuse
    float w2 = waveReduceSum(ss2);
    if (lane == 0) sbuf[wid] = w2;
    __syncthreads();
    if (tid == 0) sq[i] = sbuf[0] + sbuf[1] + sbuf[2] + sbuf[3];
}

// Kernel B: dist[i][j] = sqrt(max(sq_i + sq_j - 2*dot(p_i,p_j), 0)) via bf16 MFMA.
// One wave per 32x32 output tile; fragment-shaped global loads (L2-resident), no LDS.
__global__ __launch_bounds__(64) void kdist(const unsigned short* __restrict__ pb,
                                            const float* __restrict__ sq,
                                            float* __restrict__ dist) {
    const int lane = threadIdx.x;
    const int r0 = blockIdx.y * 32;
    const int c0 = blockIdx.x * 32;
    const int rl = lane & 15;
    const int koff = (lane >> 4) * 8;

    f32x4 acc00 = {0.f, 0.f, 0.f, 0.f};
    f32x4 acc01 = {0.f, 0.f, 0.f, 0.f};
    f32x4 acc10 = {0.f, 0.f, 0.f, 0.f};
    f32x4 acc11 = {0.f, 0.f, 0.f, 0.f};

    const unsigned short* pa0 = pb + (r0 + rl) * BS;
    const unsigned short* pa1 = pb + (r0 + rl + 16) * BS;
    const unsigned short* pb0 = pb + (c0 + rl) * BS;
    const unsigned short* pb1 = pb + (c0 + rl + 16) * BS;

#pragma unroll 4
    for (int ks = 0; ks < 16; ++ks) {
        const int k = ks * 32 + koff;
        short8 a0 = *(const short8*)(pa0 + k);
        short8 a1 = *(const short8*)(pa1 + k);
        short8 b0 = *(const short8*)(pb0 + k);
        short8 b1 = *(const short8*)(pb1 + k);
        acc00 = __builtin_amdgcn_mfma_f32_16x16x32_bf16(a0, b0, acc00, 0, 0, 0);
        acc01 = __builtin_amdgcn_mfma_f32_16x16x32_bf16(a0, b1, acc01, 0, 0, 0);
        acc10 = __builtin_amdgcn_mfma_f32_16x16x32_bf16(a1, b0, acc10, 0, 0, 0);
        acc11 = __builtin_amdgcn_mfma_f32_16x16x32_bf16(a1, b1, acc11, 0, 0, 0);
    }

    // C/D layout: col = lane&15, row = (lane>>4)*4 + reg  [m89]
    const int rbase = (lane >> 4) * 4;
#pragma unroll
    for (int fr = 0; fr < 2; ++fr) {
#pragma unroll
        for (int fc = 0; fc < 2; ++fc) {
            f32x4 v = (fr == 0) ? (fc == 0 ? acc00 : acc01) : (fc == 0 ? acc10 : acc11);
            const int col = c0 + fc * 16 + rl;
            const float sqc = sq[col];
#pragma unroll
            for (int r = 0; r < 4; ++r) {
                const int row = r0 + fr * 16 + rbase + r;
                float d2 = sq[row] + sqc - 2.0f * v[r];
                d2 = fmaxf(d2, 0.f);
                dist[row * BS + col] = sqrtf(d2);
            }
        }
    }
}

// Kernel C: one block per anchor i. Distances in registers, masks via sentinels,
// j broadcast via readlane. NO global atomics — plain per-anchor partial stores.
__global__ __launch_bounds__(256) void ktriplet(const float* __restrict__ dist,
                                                const int* __restrict__ target,
                                                float* __restrict__ psum,
                                                float* __restrict__ pcnt) {
    const int i = blockIdx.x;
    const int tid = threadIdx.x;
    const int lane = tid & 63;
    const int w = tid >> 6;
    __shared__ float sbuf[4];
    __shared__ float cbuf[4];

    float sum = 0.f;
    float cnt = 0.f;

    if (target[i] == 1) {
        // per-thread registers: slot r covers index idx = r*64 + lane
        float dkn[8];      // negative-masked (k-role):  d or +1e30
        float dkm_all[8];  // positive-masked (j-role):  d or -1e9
#pragma unroll
        for (int r = 0; r < 8; ++r) {
            const int idx = r * 64 + lane;
            const float d = dist[i * BS + idx];   // coalesced, L2-hot
            const int t = target[idx];
            dkn[r] = (t == 0) ? d : 1e30f;
            dkm_all[r] = (t == 1 && idx != i) ? d : -1e9f;
        }
        // wave w covers j in [w*128, w*128+128): two 64-wide register chunks
        const int rj0 = w * 2;
        float jreg0 = dkm_all[0], jreg1 = dkm_all[1];
        jreg0 = (rj0 == 2) ? dkm_all[2] : jreg0;
        jreg1 = (rj0 == 2) ? dkm_all[3] : jreg1;
        jreg0 = (rj0 == 4) ? dkm_all[4] : jreg0;
        jreg1 = (rj0 == 4) ? dkm_all[5] : jreg1;
        jreg0 = (rj0 == 6) ? dkm_all[6] : jreg0;
        jreg1 = (rj0 == 6) ? dkm_all[7] : jreg1;

        float s0 = 0.f, s1 = 0.f;
        float c0 = 0.f, c1 = 0.f;
#pragma unroll
        for (int jj = 0; jj < 64; ++jj) {
            const float bc0 = __int_as_float(
                __builtin_amdgcn_readlane(__float_as_int(jreg0), jj));
            const float tj0 = bc0 + MARGIN;
#pragma unroll
            for (int r = 0; r < 4; ++r) {
                const float v = tj0 - dkn[r];
                s0 += fmaxf(v, 0.f);
                c0 += (v > 0.f) ? 1.f : 0.f;
            }
#pragma unroll
            for (int r = 4; r < 8; ++r) {
                const float v = tj0 - dkn[r];
                s1 += fmaxf(v, 0.f);
                c1 += (v > 0.f) ? 1.f : 0.f;
            }
            const float bc1 = __int_as_float(
                __builtin_amdgcn_readlane(__float_as_int(jreg1), jj));
            const float tj1 = bc1 + MARGIN;
#pragma unroll
            for (int r = 0; r < 4; ++r) {
                const float v = tj1 - dkn[r];
                s0 += fmaxf(v, 0.f);
                c0 += (v > 0.f) ? 1.f : 0.f;
            }
#pragma unroll
            for (int r = 4; r < 8; ++r) {
                const float v = tj1 - dkn[r];
                s1 += fmaxf(v, 0.f);
                c1 += (v > 0.f) ? 1.f : 0.f;
            }
        }
        sum = s0 + s1;
        cnt = c0 + c1;
    }

    float wsm = waveReduceSum(sum);
    float wc = waveReduceSum(cnt);
    if (lane == 0) { sbuf[w] = wsm; cbuf[w] = wc; }
    __syncthreads();
    if (tid == 0) {
        psum[i] = sbuf[0] + sbuf[1] + sbuf[2] + sbuf[3];
        pcnt[i] = cbuf[0] + cbuf[1] + cbuf[2] + cbuf[3];
    }
}

// Kernel D: final reduce over 512 partials + divide.
__global__ __launch_bounds__(256) void kfinal(const float* __restrict__ psum,
                                              const float* __restrict__ pcnt,
                                              float* __restrict__ out) {
    const int tid = threadIdx.x;
    __shared__ float sbuf[4];
    __shared__ float cbuf[4];
    float s = psum[tid] + psum[tid + 256];
    float c = pcnt[tid] + pcnt[tid + 256];
    float wsm = waveReduceSum(s);
    float wc = waveReduceSum(c);
    const int lane = tid & 63, wid = tid >> 6;
    if (lane == 0) { sbuf[wid] = wsm; cbuf[wid] = wc; }
    __syncthreads();
    if (tid == 0) {
        float total = sbuf[0] + sbuf[1] + sbuf[2] + sbuf[3];
        float cn = cbuf[0] + cbuf[1] + cbuf[2] + cbuf[3];
        out[0] = total / (cn + 1e-7f);
    }
}

extern "C" void kernel_launch(void* const* d_in, const int* in_sizes, int n_in,
                              void* d_out, int out_size, void* d_ws, size_t ws_size,
                              hipStream_t stream) {
    const float* pred = (const float*)d_in[0];
    const int* target = (const int*)d_in[1];
    float* out = (float*)d_out;
    char* base = (char*)d_ws;

    unsigned short* pbuf = (unsigned short*)base;   // 512*512*2B = 512 KB
    float* dist = (float*)(base + 524288);          // 1 MB
    float* sq = (float*)(base + 1572864);           // 2 KB
    float* psum = (float*)(base + 1574912);         // 2 KB
    float* pcnt = (float*)(base + 1576960);         // 2 KB

    knorm<<<512, 256, 0, stream>>>(pred, pbuf, sq);
    dim3 gb(16, 16);
    kdist<<<gb, 64, 0, stream>>>(pbuf, sq, dist);
    ktriplet<<<512, 256, 0, stream>>>(dist, target, psum, pcnt);
    kfinal<<<1, 256, 0, stream>>>(psum, pcnt, out);
}

// Round 7
// 37.778 us; speedup vs baseline: 1.4869x; 1.0215x over previous
//
#include <hip/hip_runtime.h>
#include <hip/hip_bf16.h>

#define BS 512
#define MARGIN 0.5f

using short8 = __attribute__((ext_vector_type(8))) short;
using f32x4 = __attribute__((ext_vector_type(4))) float;

// Kernel A: one wave per row. L2-normalize, write p_bf16 + sq. Block 0 zeroes done_g.
__global__ __launch_bounds__(64) void knorm(const float* __restrict__ pred,
                                            unsigned short* __restrict__ pb,
                                            float* __restrict__ sq,
                                            unsigned int* __restrict__ done_g) {
    const int i = blockIdx.x;
    const int lane = threadIdx.x;
    if (i == 0 && lane == 0) *done_g = 0u;
    const f32x4* src = (const f32x4*)(pred + i * BS);
    const f32x4 x0 = src[lane * 2];
    const f32x4 x1 = src[lane * 2 + 1];
    float p[8] = {x0[0], x0[1], x0[2], x0[3], x1[0], x1[1], x1[2], x1[3]};
    float ss = 0.f;
#pragma unroll
    for (int r = 0; r < 8; ++r) ss += p[r] * p[r];
#pragma unroll
    for (int o = 32; o > 0; o >>= 1) ss += __shfl_xor(ss, o, 64);
    const float m = fmaxf(sqrtf(ss), 1e-10f);
    const float inv = 1.0f / m;
    float s2 = 0.f;
#pragma unroll
    for (int r = 0; r < 8; ++r) { p[r] *= inv; s2 += p[r] * p[r]; }
#pragma unroll
    for (int o = 32; o > 0; o >>= 1) s2 += __shfl_xor(s2, o, 64);
    if (lane == 0) sq[i] = s2;
    short8 o8;
#pragma unroll
    for (int r = 0; r < 8; ++r) {
        __hip_bfloat16 h = __float2bfloat16(p[r]);
        o8[r] = *(short*)&h;
    }
    *(short8*)(pb + i * BS + lane * 8) = o8;
}

// Kernel B: dist[i][j] = sqrt(max(sq_i + sq_j - 2*dot(p_i,p_j), 0)) via bf16 MFMA.
// One wave per 32x32 output tile; fragment-shaped global loads (L2-resident), no LDS.
__global__ __launch_bounds__(64) void kdist(const unsigned short* __restrict__ pb,
                                            const float* __restrict__ sq,
                                            float* __restrict__ dist) {
    const int lane = threadIdx.x;
    const int r0 = blockIdx.y * 32;
    const int c0 = blockIdx.x * 32;
    const int rl = lane & 15;
    const int koff = (lane >> 4) * 8;

    f32x4 acc00 = {0.f, 0.f, 0.f, 0.f};
    f32x4 acc01 = {0.f, 0.f, 0.f, 0.f};
    f32x4 acc10 = {0.f, 0.f, 0.f, 0.f};
    f32x4 acc11 = {0.f, 0.f, 0.f, 0.f};

    const unsigned short* pa0 = pb + (r0 + rl) * BS;
    const unsigned short* pa1 = pb + (r0 + rl + 16) * BS;
    const unsigned short* pb0 = pb + (c0 + rl) * BS;
    const unsigned short* pb1 = pb + (c0 + rl + 16) * BS;

#pragma unroll 4
    for (int ks = 0; ks < 16; ++ks) {
        const int k = ks * 32 + koff;
        short8 a0 = *(const short8*)(pa0 + k);
        short8 a1 = *(const short8*)(pa1 + k);
        short8 b0 = *(const short8*)(pb0 + k);
        short8 b1 = *(const short8*)(pb1 + k);
        acc00 = __builtin_amdgcn_mfma_f32_16x16x32_bf16(a0, b0, acc00, 0, 0, 0);
        acc01 = __builtin_amdgcn_mfma_f32_16x16x32_bf16(a0, b1, acc01, 0, 0, 0);
        acc10 = __builtin_amdgcn_mfma_f32_16x16x32_bf16(a1, b0, acc10, 0, 0, 0);
        acc11 = __builtin_amdgcn_mfma_f32_16x16x32_bf16(a1, b1, acc11, 0, 0, 0);
    }

    // C/D layout: col = lane&15, row = (lane>>4)*4 + reg  [m89]
    const int rbase = (lane >> 4) * 4;
#pragma unroll
    for (int fr = 0; fr < 2; ++fr) {
#pragma unroll
        for (int fc = 0; fc < 2; ++fc) {
            f32x4 v = (fr == 0) ? (fc == 0 ? acc00 : acc01) : (fc == 0 ? acc10 : acc11);
            const int col = c0 + fc * 16 + rl;
            const float sqc = sq[col];
#pragma unroll
            for (int r = 0; r < 4; ++r) {
                const int row = r0 + fr * 16 + rbase + r;
                float d2 = sq[row] + sqc - 2.0f * v[r];
                d2 = fmaxf(d2, 0.f);
                dist[row * BS + col] = sqrtf(d2);
            }
        }
    }
}

// Kernel C: one block per anchor i. Distances in registers; masks via sentinels;
// margin folded into j-values; j broadcast via readlane; count via ballot+SALU
// popcount. Per-anchor partial stores + done-counter; last block does the final
// fixed-order reduce (deterministic).
__global__ __launch_bounds__(256) void ktriplet(const float* __restrict__ dist,
                                                const int* __restrict__ target,
                                                float* __restrict__ psum,
                                                float* __restrict__ pcnt,
                                                unsigned int* __restrict__ done_g,
                                                float* __restrict__ out) {
    const int i = blockIdx.x;
    const int tid = threadIdx.x;
    const int lane = tid & 63;
    const int w = tid >> 6;
    __shared__ float sbuf[4];
    __shared__ float cbuf[4];
    __shared__ unsigned int slast;

    float sum = 0.f;
    float cnt = 0.f;

    if (target[i] == 1) {
        // slot r covers index idx = r*64 + lane
        float dkn[8];  // negative-masked (k-role): d       or +1e30
        float dkm[8];  // positive-masked (j-role): d + M   or -1e9
#pragma unroll
        for (int r = 0; r < 8; ++r) {
            const int idx = r * 64 + lane;
            const float d = dist[i * BS + idx];  // coalesced, L2/L3-hot
            const int t = target[idx];
            dkn[r] = (t == 0) ? d : 1e30f;
            dkm[r] = (t == 1 && idx != i) ? d + MARGIN : -1e9f;
        }
        // wave w covers j in [w*128, w*128+128): two 64-wide register chunks
        const int rj0 = w * 2;
        float jreg0 = dkm[0], jreg1 = dkm[1];
        jreg0 = (rj0 == 2) ? dkm[2] : jreg0;  jreg1 = (rj0 == 2) ? dkm[3] : jreg1;
        jreg0 = (rj0 == 4) ? dkm[4] : jreg0;  jreg1 = (rj0 == 4) ? dkm[5] : jreg1;
        jreg0 = (rj0 == 6) ? dkm[6] : jreg0;  jreg1 = (rj0 == 6) ? dkm[7] : jreg1;

        float sA = 0.f, sB = 0.f, sC = 0.f, sD = 0.f;
        unsigned int cw = 0;  // wave-uniform (SGPR): ballot popcounts

#define HINGE8(TJ)                                                             \
    do {                                                                       \
        const float v0 = (TJ)-dkn[0];                                          \
        sA += fmaxf(v0, 0.f); cw += __popcll(__ballot(v0 > 0.f));              \
        const float v1 = (TJ)-dkn[1];                                          \
        sB += fmaxf(v1, 0.f); cw += __popcll(__ballot(v1 > 0.f));              \
        const float v2 = (TJ)-dkn[2];                                          \
        sC += fmaxf(v2, 0.f); cw += __popcll(__ballot(v2 > 0.f));              \
        const float v3 = (TJ)-dkn[3];                                          \
        sD += fmaxf(v3, 0.f); cw += __popcll(__ballot(v3 > 0.f));              \
        const float v4 = (TJ)-dkn[4];                                          \
        sA += fmaxf(v4, 0.f); cw += __popcll(__ballot(v4 > 0.f));              \
        const float v5 = (TJ)-dkn[5];                                          \
        sB += fmaxf(v5, 0.f); cw += __popcll(__ballot(v5 > 0.f));              \
        const float v6 = (TJ)-dkn[6];                                          \
        sC += fmaxf(v6, 0.f); cw += __popcll(__ballot(v6 > 0.f));              \
        const float v7 = (TJ)-dkn[7];                                          \
        sD += fmaxf(v7, 0.f); cw += __popcll(__ballot(v7 > 0.f));              \
    } while (0)

#pragma unroll
        for (int jj = 0; jj < 64; ++jj) {
            const float tj0 = __int_as_float(
                __builtin_amdgcn_readlane(__float_as_int(jreg0), jj));
            HINGE8(tj0);
            const float tj1 = __int_as_float(
                __builtin_amdgcn_readlane(__float_as_int(jreg1), jj));
            HINGE8(tj1);
        }
#undef HINGE8
        sum = (sA + sB) + (sC + sD);
        cnt = (float)cw;  // wave-total already; exact (<= 2^17)
    }

    // per-wave: sum needs lane-reduce; cnt is already wave-total (uniform)
    float wsm = sum;
#pragma unroll
    for (int o = 32; o > 0; o >>= 1) wsm += __shfl_xor(wsm, o, 64);
    if (lane == 0) { sbuf[w] = wsm; cbuf[w] = cnt; }
    __syncthreads();
    if (tid == 0) {
        const float bsum = (sbuf[0] + sbuf[1]) + (sbuf[2] + sbuf[3]);
        const float bcnt = (cbuf[0] + cbuf[1]) + (cbuf[2] + cbuf[3]);
        psum[i] = bsum;
        pcnt[i] = bcnt;
        __threadfence();  // publish partials (release)
        slast = (atomicAdd(done_g, 1u) == (unsigned int)(BS - 1)) ? 1u : 0u;
    }
    __syncthreads();
    if (slast != 0 && tid < 64) {
        __threadfence();  // acquire
        float s = 0.f, c = 0.f;
#pragma unroll
        for (int r = 0; r < 8; ++r) {
            s += psum[r * 64 + tid];
            c += pcnt[r * 64 + tid];
        }
#pragma unroll
        for (int o = 32; o > 0; o >>= 1) {
            s += __shfl_xor(s, o, 64);
            c += __shfl_xor(c, o, 64);
        }
        if (tid == 0) out[0] = s / (c + 1e-7f);
    }
}

extern "C" void kernel_launch(void* const* d_in, const int* in_sizes, int n_in,
                              void* d_out, int out_size, void* d_ws, size_t ws_size,
                              hipStream_t stream) {
    const float* pred = (const float*)d_in[0];
    const int* target = (const int*)d_in[1];
    float* out = (float*)d_out;
    char* base = (char*)d_ws;

    unsigned short* pbuf = (unsigned short*)base;   // 512 KB
    float* dist = (float*)(base + 524288);          // 1 MB
    float* sq = (float*)(base + 1572864);           // 2 KB
    float* psum = (float*)(base + 1574912);         // 2 KB
    float* pcnt = (float*)(base + 1576960);         // 2 KB
    unsigned int* done_g = (unsigned int*)(base + 1579008);

    knorm<<<512, 64, 0, stream>>>(pred, pbuf, sq, done_g);
    dim3 gb(16, 16);
    kdist<<<gb, 64, 0, stream>>>(pbuf, sq, dist);
    ktriplet<<<512, 256, 0, stream>>>(dist, target, psum, pcnt, done_g, out);
}